// Round 1
// baseline (134.128 us; speedup 1.0000x reference)
//
#include <hip/hip_runtime.h>
#include <math.h>

namespace {

constexpr int BB   = 4096;
constexpr int INF  = 32;
constexpr int H    = 128;
constexpr int HH   = 64;
constexpr int ZD   = 192;   // H + HH
constexpr int SPW  = 8;     // samples per pod (128 threads)
constexpr int PODS = 2;     // pods per block
constexpr float LNEPS = 1e-5f;

__device__ __forceinline__ float elu1(float v) {
    return v > 0.f ? v : (__expf(v) - 1.f);
}

__global__ __launch_bounds__(256) void fused_sthgat(
    const float* __restrict__ x, const int* __restrict__ sid,
    const float* __restrict__ Wp, const float* __restrict__ bp,
    const float* __restrict__ emb, const float* __restrict__ gatW,
    const float* __restrict__ W1, const float* __restrict__ b1,
    const float* __restrict__ g1, const float* __restrict__ be1,
    const float* __restrict__ W2, const float* __restrict__ b2,
    const float* __restrict__ g2, const float* __restrict__ be2,
    const float* __restrict__ Wo, const float* __restrict__ bo,
    float* __restrict__ out)
{
    __shared__ __align__(16) float Abuf[PODS][SPW][ZD];
    __shared__ __align__(16) float Bbuf[PODS][SPW][ZD];
    __shared__ float Rbuf[PODS][2][SPW][2];

    const int tid  = threadIdx.x;
    const int pod  = tid >> 7;          // 0..1
    const int g    = tid & 127;         // channel 0..127
    const int lane = tid & 63;
    const int wid  = (tid >> 6) & 1;    // wave within pod
    const int sbase = blockIdx.x * (PODS * SPW) + pod * SPW;

    float* Af = &Abuf[pod][0][0];
    float* Bf = &Bbuf[pod][0][0];

    // ---- S0: stage x rows (8 x 32 contiguous floats) into Af ----
    {
        const float2* xs = reinterpret_cast<const float2*>(x + (size_t)sbase * INF);
        reinterpret_cast<float2*>(Af)[g] = xs[g];
    }
    __syncthreads();

    // ---- S1: h0 = x @ Wp + bp ----
    float acc[SPW];
#pragma unroll
    for (int s = 0; s < SPW; ++s) acc[s] = 0.f;
#pragma unroll
    for (int f = 0; f < INF; f += 4) {
        const float w0 = Wp[(f + 0) * H + g];
        const float w1 = Wp[(f + 1) * H + g];
        const float w2 = Wp[(f + 2) * H + g];
        const float w3 = Wp[(f + 3) * H + g];
#pragma unroll
        for (int s = 0; s < SPW; ++s) {
            const float4 hv = *reinterpret_cast<const float4*>(Af + s * INF + f);
            acc[s] += hv.x * w0 + hv.y * w1 + hv.z * w2 + hv.w * w3;
        }
    }
    {
        const float bpv = bp[g];
#pragma unroll
        for (int s = 0; s < SPW; ++s) acc[s] += bpv;
    }

    // ---- GAT layer 1 (node-collapsed): h = h + elu(h @ gW0) ----
    {
#pragma unroll
        for (int s = 0; s < SPW; ++s) Bf[s * ZD + g] = acc[s];
        __syncthreads();
        float t[SPW];
#pragma unroll
        for (int s = 0; s < SPW; ++s) t[s] = 0.f;
        const float* wl = gatW;  // layer 0
        for (int f = 0; f < H; f += 4) {
            const float w0 = wl[(f + 0) * H + g];
            const float w1 = wl[(f + 1) * H + g];
            const float w2 = wl[(f + 2) * H + g];
            const float w3 = wl[(f + 3) * H + g];
#pragma unroll
            for (int s = 0; s < SPW; ++s) {
                const float4 hv = *reinterpret_cast<const float4*>(Bf + s * ZD + f);
                t[s] += hv.x * w0 + hv.y * w1 + hv.z * w2 + hv.w * w3;
            }
        }
#pragma unroll
        for (int s = 0; s < SPW; ++s) acc[s] += elu1(t[s]);
    }

    // ---- GAT layer 2: h = h + elu(h @ gW1) ----
    {
#pragma unroll
        for (int s = 0; s < SPW; ++s) Af[s * ZD + g] = acc[s];
        __syncthreads();
        float t[SPW];
#pragma unroll
        for (int s = 0; s < SPW; ++s) t[s] = 0.f;
        const float* wl = gatW + H * H;  // layer 1
        for (int f = 0; f < H; f += 4) {
            const float w0 = wl[(f + 0) * H + g];
            const float w1 = wl[(f + 1) * H + g];
            const float w2 = wl[(f + 2) * H + g];
            const float w3 = wl[(f + 3) * H + g];
#pragma unroll
            for (int s = 0; s < SPW; ++s) {
                const float4 hv = *reinterpret_cast<const float4*>(Af + s * ZD + f);
                t[s] += hv.x * w0 + hv.y * w1 + hv.z * w2 + hv.w * w3;
            }
        }
#pragma unroll
        for (int s = 0; s < SPW; ++s) acc[s] += elu1(t[s]);
    }

    // ---- S3: z = [h2, emb[sid]] -> Bf ; u = z @ W1 + b1 ----
    float u[SPW];
    {
#pragma unroll
        for (int s = 0; s < SPW; ++s) Bf[s * ZD + g] = acc[s];
        const int j  = g & 63;
        const int sh = g >> 6;
#pragma unroll
        for (int k = 0; k < 4; ++k) {
            const int s  = sh + 2 * k;
            const int st = sid[sbase + s];
            Bf[s * ZD + H + j] = emb[st * HH + j];
        }
        __syncthreads();
#pragma unroll
        for (int s = 0; s < SPW; ++s) u[s] = 0.f;
        for (int f = 0; f < ZD; f += 4) {
            const float w0 = W1[(f + 0) * H + g];
            const float w1 = W1[(f + 1) * H + g];
            const float w2 = W1[(f + 2) * H + g];
            const float w3 = W1[(f + 3) * H + g];
#pragma unroll
            for (int s = 0; s < SPW; ++s) {
                const float4 hv = *reinterpret_cast<const float4*>(Bf + s * ZD + f);
                u[s] += hv.x * w0 + hv.y * w1 + hv.z * w2 + hv.w * w3;
            }
        }
        const float b1v = b1[g];
#pragma unroll
        for (int s = 0; s < SPW; ++s) u[s] += b1v;
    }

    // ---- LN1 + relu -> z1 in Af ----
    {
        float su[SPW], sq[SPW];
#pragma unroll
        for (int s = 0; s < SPW; ++s) { su[s] = u[s]; sq[s] = u[s] * u[s]; }
#pragma unroll
        for (int off = 32; off >= 1; off >>= 1) {
#pragma unroll
            for (int s = 0; s < SPW; ++s) {
                su[s] += __shfl_xor(su[s], off, 64);
                sq[s] += __shfl_xor(sq[s], off, 64);
            }
        }
        if (lane == 0) {
#pragma unroll
            for (int s = 0; s < SPW; ++s) {
                Rbuf[pod][wid][s][0] = su[s];
                Rbuf[pod][wid][s][1] = sq[s];
            }
        }
        __syncthreads();
        const float g1v = g1[g], be1v = be1[g];
#pragma unroll
        for (int s = 0; s < SPW; ++s) {
            const float tot = Rbuf[pod][0][s][0] + Rbuf[pod][1][s][0];
            const float tq  = Rbuf[pod][0][s][1] + Rbuf[pod][1][s][1];
            const float m   = tot * (1.f / H);
            const float var = tq * (1.f / H) - m * m;
            const float rs  = rsqrtf(var + LNEPS);
            const float z   = (u[s] - m) * rs * g1v + be1v;
            Af[s * ZD + g] = fmaxf(z, 0.f);
        }
        __syncthreads();
    }

    // ---- S5: v = z1 @ W2 + b2 ; LN2 + relu ; out = z2 @ Wo + bo ----
    {
        const int c   = lane;        // channel 0..63
        const int sb2 = wid * 4;     // wave0 -> samples 0..3, wave1 -> 4..7
        float v[4] = {0.f, 0.f, 0.f, 0.f};
        for (int f = 0; f < H; f += 4) {
            const float w0 = W2[(f + 0) * HH + c];
            const float w1 = W2[(f + 1) * HH + c];
            const float w2 = W2[(f + 2) * HH + c];
            const float w3 = W2[(f + 3) * HH + c];
#pragma unroll
            for (int k = 0; k < 4; ++k) {
                const float4 hv = *reinterpret_cast<const float4*>(Af + (sb2 + k) * ZD + f);
                v[k] += hv.x * w0 + hv.y * w1 + hv.z * w2 + hv.w * w3;
            }
        }
        const float b2v = b2[c];
#pragma unroll
        for (int k = 0; k < 4; ++k) v[k] += b2v;

        float su[4], sq[4];
#pragma unroll
        for (int k = 0; k < 4; ++k) { su[k] = v[k]; sq[k] = v[k] * v[k]; }
#pragma unroll
        for (int off = 32; off >= 1; off >>= 1) {
#pragma unroll
            for (int k = 0; k < 4; ++k) {
                su[k] += __shfl_xor(su[k], off, 64);
                sq[k] += __shfl_xor(sq[k], off, 64);
            }
        }
        const float g2v = g2[c], be2v = be2[c], wov = Wo[c];
        float po[4];
#pragma unroll
        for (int k = 0; k < 4; ++k) {
            const float m   = su[k] * (1.f / HH);
            const float var = sq[k] * (1.f / HH) - m * m;
            const float rs  = rsqrtf(var + LNEPS);
            const float z2  = fmaxf((v[k] - m) * rs * g2v + be2v, 0.f);
            po[k] = z2 * wov;
        }
#pragma unroll
        for (int off = 32; off >= 1; off >>= 1) {
#pragma unroll
            for (int k = 0; k < 4; ++k) po[k] += __shfl_xor(po[k], off, 64);
        }
        if (lane < 4) {
            const float r = (lane == 0) ? po[0] : (lane == 1) ? po[1]
                          : (lane == 2) ? po[2] : po[3];
            out[sbase + sb2 + lane] = r + bo[0];
        }
    }
}

}  // namespace

extern "C" void kernel_launch(void* const* d_in, const int* in_sizes, int n_in,
                              void* d_out, int out_size, void* d_ws, size_t ws_size,
                              hipStream_t stream)
{
    const float* x    = (const float*)d_in[0];
    const int*   sid  = (const int*)d_in[1];
    // d_in[2] edge_index, d_in[3] edge_weight, d_in[8] gat_a: unused —
    // node-uniform broadcast + row-softmax makes the GAT aggregation collapse
    // to elu(h @ W) independent of the graph.
    const float* Wp   = (const float*)d_in[4];
    const float* bp   = (const float*)d_in[5];
    const float* emb  = (const float*)d_in[6];
    const float* gatW = (const float*)d_in[7];
    const float* W1   = (const float*)d_in[9];
    const float* b1   = (const float*)d_in[10];
    const float* g1   = (const float*)d_in[11];
    const float* be1  = (const float*)d_in[12];
    const float* W2   = (const float*)d_in[13];
    const float* b2   = (const float*)d_in[14];
    const float* g2   = (const float*)d_in[15];
    const float* be2  = (const float*)d_in[16];
    const float* Wo   = (const float*)d_in[17];
    const float* bo   = (const float*)d_in[18];
    float* out = (float*)d_out;

    dim3 grid(BB / (PODS * SPW));   // 256 blocks -> 1 per CU
    dim3 block(PODS * 128);         // 256 threads
    hipLaunchKernelGGL(fused_sthgat, grid, block, 0, stream,
                       x, sid, Wp, bp, emb, gatW, W1, b1, g1, be1,
                       W2, b2, g2, be2, Wo, bo, out);
}

// Round 2
// 123.816 us; speedup vs baseline: 1.0833x; 1.0833x over previous
//
#include <hip/hip_runtime.h>
#include <math.h>

namespace {

constexpr int BB   = 4096;
constexpr int INF  = 32;
constexpr int H    = 128;
constexpr int HH   = 64;
constexpr int ZD   = 192;   // H + HH
constexpr int SPW  = 4;     // samples per pod (128 threads)
constexpr int PODS = 2;     // pods per block
constexpr float LNEPS = 1e-5f;

__device__ __forceinline__ float elu1(float v) {
    return v > 0.f ? v : (__expf(v) - 1.f);
}

// t[s] += sum_f Sf[s*STRIDE + f] * W[f*LDW + g]  for f in [0, D)
// 16-row register double-buffered weight prefetch; fully static indexing so
// nothing lands in scratch (rule #20). 16 independent global loads stay in
// flight while the previous chunk's FMAs execute.
template<int D, int LDW, int NS, int STRIDE>
__device__ __forceinline__ void gemm_acc(const float* __restrict__ W, int g,
                                         const float* __restrict__ Sf, float* t)
{
    constexpr int NC = D / 16;
    static_assert(NC >= 2 && (NC & 1) == 0, "even chunk count");
    float wa[16], wb[16];
#pragma unroll
    for (int r = 0; r < 16; ++r) wa[r] = W[r * LDW + g];
#pragma unroll
    for (int c = 0; c < NC; c += 2) {
        // prefetch chunk c+1 into wb
#pragma unroll
        for (int r = 0; r < 16; ++r) wb[r] = W[((c + 1) * 16 + r) * LDW + g];
        // compute chunk c from wa (LDS broadcast reads, conflict-free)
#pragma unroll
        for (int rr = 0; rr < 16; rr += 4) {
#pragma unroll
            for (int s = 0; s < NS; ++s) {
                const float4 hv = *reinterpret_cast<const float4*>(
                    Sf + s * STRIDE + c * 16 + rr);
                t[s] += hv.x * wa[rr + 0] + hv.y * wa[rr + 1]
                      + hv.z * wa[rr + 2] + hv.w * wa[rr + 3];
            }
        }
        // prefetch chunk c+2 into wa
        if (c + 2 < NC) {
#pragma unroll
            for (int r = 0; r < 16; ++r) wa[r] = W[((c + 2) * 16 + r) * LDW + g];
        }
        // compute chunk c+1 from wb
#pragma unroll
        for (int rr = 0; rr < 16; rr += 4) {
#pragma unroll
            for (int s = 0; s < NS; ++s) {
                const float4 hv = *reinterpret_cast<const float4*>(
                    Sf + s * STRIDE + (c + 1) * 16 + rr);
                t[s] += hv.x * wb[rr + 0] + hv.y * wb[rr + 1]
                      + hv.z * wb[rr + 2] + hv.w * wb[rr + 3];
            }
        }
    }
}

__global__ __launch_bounds__(256) void fused_sthgat(
    const float* __restrict__ x, const int* __restrict__ sid,
    const float* __restrict__ Wp, const float* __restrict__ bp,
    const float* __restrict__ emb, const float* __restrict__ gatW,
    const float* __restrict__ W1, const float* __restrict__ b1,
    const float* __restrict__ g1, const float* __restrict__ be1,
    const float* __restrict__ W2, const float* __restrict__ b2,
    const float* __restrict__ g2, const float* __restrict__ be2,
    const float* __restrict__ Wo, const float* __restrict__ bo,
    float* __restrict__ out)
{
    __shared__ __align__(16) float Abuf[PODS][SPW][ZD];
    __shared__ __align__(16) float Bbuf[PODS][SPW][ZD];
    __shared__ float Rbuf[PODS][2][SPW][2];

    const int tid  = threadIdx.x;
    const int pod  = tid >> 7;          // 0..1
    const int g    = tid & 127;         // channel 0..127
    const int lane = tid & 63;
    const int wid  = (tid >> 6) & 1;    // wave within pod
    const int sbase = blockIdx.x * (PODS * SPW) + pod * SPW;

    float* Af = &Abuf[pod][0][0];
    float* Bf = &Bbuf[pod][0][0];

    // ---- S0: stage x rows (SPW x 32 contiguous floats = 128) into Af ----
    Af[g] = x[(size_t)sbase * INF + g];
    __syncthreads();

    // ---- S1: h0 = x @ Wp + bp ----
    float acc[SPW] = {0.f, 0.f, 0.f, 0.f};
    gemm_acc<INF, H, SPW, INF>(Wp, g, Af, acc);
    {
        const float bpv = bp[g];
#pragma unroll
        for (int s = 0; s < SPW; ++s) acc[s] += bpv;
    }

    // ---- GAT layer 1 (node-collapsed): h = h + elu(h @ gW0) ----
    {
#pragma unroll
        for (int s = 0; s < SPW; ++s) Bf[s * ZD + g] = acc[s];
        __syncthreads();
        float t[SPW] = {0.f, 0.f, 0.f, 0.f};
        gemm_acc<H, H, SPW, ZD>(gatW, g, Bf, t);
#pragma unroll
        for (int s = 0; s < SPW; ++s) acc[s] += elu1(t[s]);
    }
    __syncthreads();

    // ---- GAT layer 2: h = h + elu(h @ gW1) ----
    {
#pragma unroll
        for (int s = 0; s < SPW; ++s) Af[s * ZD + g] = acc[s];
        __syncthreads();
        float t[SPW] = {0.f, 0.f, 0.f, 0.f};
        gemm_acc<H, H, SPW, ZD>(gatW + H * H, g, Af, t);
#pragma unroll
        for (int s = 0; s < SPW; ++s) acc[s] += elu1(t[s]);
    }
    __syncthreads();

    // ---- S3: z = [h2, emb[sid]] -> Bf ; u = z @ W1 + b1 ----
    float u[SPW];
    {
#pragma unroll
        for (int s = 0; s < SPW; ++s) Bf[s * ZD + g] = acc[s];
        const int j  = g & 63;
        const int sh = g >> 6;
#pragma unroll
        for (int k = 0; k < 2; ++k) {
            const int s  = sh + 2 * k;
            const int st = sid[sbase + s];
            Bf[s * ZD + H + j] = emb[st * HH + j];
        }
        __syncthreads();
        float t[SPW] = {0.f, 0.f, 0.f, 0.f};
        gemm_acc<ZD, H, SPW, ZD>(W1, g, Bf, t);
        const float b1v = b1[g];
#pragma unroll
        for (int s = 0; s < SPW; ++s) u[s] = t[s] + b1v;
    }

    // ---- LN1 + relu -> z1 in Af ----
    {
        float su[SPW], sq[SPW];
#pragma unroll
        for (int s = 0; s < SPW; ++s) { su[s] = u[s]; sq[s] = u[s] * u[s]; }
#pragma unroll
        for (int off = 32; off >= 1; off >>= 1) {
#pragma unroll
            for (int s = 0; s < SPW; ++s) {
                su[s] += __shfl_xor(su[s], off, 64);
                sq[s] += __shfl_xor(sq[s], off, 64);
            }
        }
        if (lane == 0) {
#pragma unroll
            for (int s = 0; s < SPW; ++s) {
                Rbuf[pod][wid][s][0] = su[s];
                Rbuf[pod][wid][s][1] = sq[s];
            }
        }
        __syncthreads();
        const float g1v = g1[g], be1v = be1[g];
#pragma unroll
        for (int s = 0; s < SPW; ++s) {
            const float tot = Rbuf[pod][0][s][0] + Rbuf[pod][1][s][0];
            const float tq  = Rbuf[pod][0][s][1] + Rbuf[pod][1][s][1];
            const float m   = tot * (1.f / H);
            const float var = tq * (1.f / H) - m * m;
            const float rs  = rsqrtf(var + LNEPS);
            const float z   = (u[s] - m) * rs * g1v + be1v;
            Af[s * ZD + g] = fmaxf(z, 0.f);
        }
        __syncthreads();
    }

    // ---- S5: v = z1 @ W2 + b2 ; LN2 + relu ; out = z2 @ Wo + bo ----
    {
        const int c   = lane;        // channel 0..63
        const int sb2 = wid * 2;     // wave0 -> samples 0..1, wave1 -> 2..3
        float v[2] = {0.f, 0.f};
        gemm_acc<H, HH, 2, ZD>(W2, c, Af + sb2 * ZD, v);
        const float b2v = b2[c];
#pragma unroll
        for (int k = 0; k < 2; ++k) v[k] += b2v;

        float su[2], sq[2];
#pragma unroll
        for (int k = 0; k < 2; ++k) { su[k] = v[k]; sq[k] = v[k] * v[k]; }
#pragma unroll
        for (int off = 32; off >= 1; off >>= 1) {
#pragma unroll
            for (int k = 0; k < 2; ++k) {
                su[k] += __shfl_xor(su[k], off, 64);
                sq[k] += __shfl_xor(sq[k], off, 64);
            }
        }
        const float g2v = g2[c], be2v = be2[c], wov = Wo[c];
        float po[2];
#pragma unroll
        for (int k = 0; k < 2; ++k) {
            const float m   = su[k] * (1.f / HH);
            const float var = sq[k] * (1.f / HH) - m * m;
            const float rs  = rsqrtf(var + LNEPS);
            const float z2  = fmaxf((v[k] - m) * rs * g2v + be2v, 0.f);
            po[k] = z2 * wov;
        }
#pragma unroll
        for (int off = 32; off >= 1; off >>= 1) {
#pragma unroll
            for (int k = 0; k < 2; ++k) po[k] += __shfl_xor(po[k], off, 64);
        }
        if (lane < 2) {
            const float r = (lane == 0) ? po[0] : po[1];
            out[sbase + sb2 + lane] = r + bo[0];
        }
    }
}

}  // namespace

extern "C" void kernel_launch(void* const* d_in, const int* in_sizes, int n_in,
                              void* d_out, int out_size, void* d_ws, size_t ws_size,
                              hipStream_t stream)
{
    const float* x    = (const float*)d_in[0];
    const int*   sid  = (const int*)d_in[1];
    // d_in[2] edge_index, d_in[3] edge_weight, d_in[8] gat_a: unused —
    // node-uniform broadcast + row-softmax makes the GAT aggregation collapse
    // to elu(h @ W) independent of the graph.
    const float* Wp   = (const float*)d_in[4];
    const float* bp   = (const float*)d_in[5];
    const float* emb  = (const float*)d_in[6];
    const float* gatW = (const float*)d_in[7];
    const float* W1   = (const float*)d_in[9];
    const float* b1   = (const float*)d_in[10];
    const float* g1   = (const float*)d_in[11];
    const float* be1  = (const float*)d_in[12];
    const float* W2   = (const float*)d_in[13];
    const float* b2   = (const float*)d_in[14];
    const float* g2   = (const float*)d_in[15];
    const float* be2  = (const float*)d_in[16];
    const float* Wo   = (const float*)d_in[17];
    const float* bo   = (const float*)d_in[18];
    float* out = (float*)d_out;

    dim3 grid(BB / (PODS * SPW));   // 512 blocks -> 2 per CU -> 8 waves/CU
    dim3 block(PODS * 128);         // 256 threads
    hipLaunchKernelGGL(fused_sthgat, grid, block, 0, stream,
                       x, sid, Wp, bp, emb, gatW, W1, b1, g1, be1,
                       W2, b2, g2, be2, Wo, bo, out);
}

// Round 3
// 104.742 us; speedup vs baseline: 1.2806x; 1.1821x over previous
//
#include <hip/hip_runtime.h>
#include <math.h>

namespace {

constexpr int INF = 32;
constexpr int H   = 128;
constexpr int HH  = 64;
constexpr int ZD  = 192;   // H + HH
constexpr int SPB = 8;     // samples per block
constexpr float LNEPS = 1e-5f;

__device__ __forceinline__ float elu1(float v) {
    return v > 0.f ? v : (__expf(v) - 1.f);
}

// t[s] += sum_{r<DK} act[s*ZD + r] * Wcol[r*LDW]
// Wcol pre-offset to &W[f0*LDW + col]; act pre-offset to &buf[f0].
// 8-row register double-buffered prefetch, fully static indexing (rule #20).
template<int DK, int LDW, int NS>
__device__ __forceinline__ void gemm_part(const float* __restrict__ Wcol,
                                          const float* __restrict__ act,
                                          float* __restrict__ t)
{
    if constexpr (DK == 8) {
        float w[8];
#pragma unroll
        for (int r = 0; r < 8; ++r) w[r] = Wcol[r * LDW];
#pragma unroll
        for (int rr = 0; rr < 8; rr += 4) {
#pragma unroll
            for (int s = 0; s < NS; ++s) {
                const float4 hv = *reinterpret_cast<const float4*>(act + s * ZD + rr);
                t[s] += hv.x * w[rr + 0] + hv.y * w[rr + 1]
                      + hv.z * w[rr + 2] + hv.w * w[rr + 3];
            }
        }
    } else {
        constexpr int NC = DK / 8;
        static_assert((NC & 1) == 0, "even chunk count");
        float wa[8], wb[8];
#pragma unroll
        for (int r = 0; r < 8; ++r) wa[r] = Wcol[r * LDW];
#pragma unroll
        for (int c = 0; c < NC; c += 2) {
#pragma unroll
            for (int r = 0; r < 8; ++r) wb[r] = Wcol[((c + 1) * 8 + r) * LDW];
#pragma unroll
            for (int rr = 0; rr < 8; rr += 4) {
#pragma unroll
                for (int s = 0; s < NS; ++s) {
                    const float4 hv = *reinterpret_cast<const float4*>(act + s * ZD + c * 8 + rr);
                    t[s] += hv.x * wa[rr + 0] + hv.y * wa[rr + 1]
                          + hv.z * wa[rr + 2] + hv.w * wa[rr + 3];
                }
            }
            if (c + 2 < NC) {
#pragma unroll
                for (int r = 0; r < 8; ++r) wa[r] = Wcol[((c + 2) * 8 + r) * LDW];
            }
#pragma unroll
            for (int rr = 0; rr < 8; rr += 4) {
#pragma unroll
                for (int s = 0; s < NS; ++s) {
                    const float4 hv = *reinterpret_cast<const float4*>(act + s * ZD + (c + 1) * 8 + rr);
                    t[s] += hv.x * wb[rr + 0] + hv.y * wb[rr + 1]
                          + hv.z * wb[rr + 2] + hv.w * wb[rr + 3];
                }
            }
        }
    }
}

__global__ __launch_bounds__(512, 4) void fused_sthgat(
    const float* __restrict__ x, const int* __restrict__ sid,
    const float* __restrict__ Wp, const float* __restrict__ bp,
    const float* __restrict__ emb, const float* __restrict__ gatW,
    const float* __restrict__ W1, const float* __restrict__ b1,
    const float* __restrict__ g1, const float* __restrict__ be1,
    const float* __restrict__ W2, const float* __restrict__ b2,
    const float* __restrict__ g2, const float* __restrict__ be2,
    const float* __restrict__ Wo, const float* __restrict__ bo,
    float* __restrict__ out)
{
    // Partials [k=4][s=8][g=128] (also reused as [k=8][s=8][c=64] for W2):
    // lanes contiguous in g/c -> conflict-free stores and loads.
    __shared__ __align__(16) float P2[4 * SPB * H];
    __shared__ __align__(16) float buf0[SPB * ZD];
    __shared__ __align__(16) float buf1[SPB * ZD];
    __shared__ float Rbuf[4][2][2][2];

    const int tid  = threadIdx.x;
    const int lane = tid & 63;
    const int wid  = tid >> 6;     // 0..7
    const int kq   = tid >> 7;     // 0..3 (K-split quarter for 128-out GEMMs)
    const int g    = tid & 127;    // output channel 0..127
    const int sbase = blockIdx.x * SPB;

    // ---- stage x: 8 samples x 32 floats into buf0 (stride ZD) ----
    if (tid < SPB * INF) {
        buf0[(tid >> 5) * ZD + (tid & 31)] = x[(size_t)sbase * INF + tid];
    }
    __syncthreads();

    // ---- S1: h0 = x @ Wp + bp  (D=32, quarter=8 rows) ----
    {
        float t[SPB] = {0,0,0,0,0,0,0,0};
        gemm_part<8, H, SPB>(Wp + (kq * 8) * H + g, buf0 + kq * 8, t);
#pragma unroll
        for (int s = 0; s < SPB; ++s) P2[kq * (SPB * H) + s * H + g] = t[s];
        __syncthreads();
        const float bpv = bp[g];
#pragma unroll
        for (int e = 0; e < 2; ++e) {
            const int s = kq * 2 + e;
            const float v = P2[0 * (SPB * H) + s * H + g] + P2[1 * (SPB * H) + s * H + g]
                          + P2[2 * (SPB * H) + s * H + g] + P2[3 * (SPB * H) + s * H + g] + bpv;
            buf1[s * ZD + g] = v;
        }
        __syncthreads();
    }

    // ---- GAT1: h = h + elu(h @ gW0)  (buf1 -> buf0) ----
    {
        float t[SPB] = {0,0,0,0,0,0,0,0};
        gemm_part<32, H, SPB>(gatW + (kq * 32) * H + g, buf1 + kq * 32, t);
#pragma unroll
        for (int s = 0; s < SPB; ++s) P2[kq * (SPB * H) + s * H + g] = t[s];
        __syncthreads();
#pragma unroll
        for (int e = 0; e < 2; ++e) {
            const int s = kq * 2 + e;
            const float v = P2[0 * (SPB * H) + s * H + g] + P2[1 * (SPB * H) + s * H + g]
                          + P2[2 * (SPB * H) + s * H + g] + P2[3 * (SPB * H) + s * H + g];
            buf0[s * ZD + g] = buf1[s * ZD + g] + elu1(v);
        }
        __syncthreads();
    }

    // ---- GAT2: h = h + elu(h @ gW1)  (buf0 -> buf1), then emb concat ----
    {
        float t[SPB] = {0,0,0,0,0,0,0,0};
        gemm_part<32, H, SPB>(gatW + H * H + (kq * 32) * H + g, buf0 + kq * 32, t);
#pragma unroll
        for (int s = 0; s < SPB; ++s) P2[kq * (SPB * H) + s * H + g] = t[s];
        __syncthreads();
#pragma unroll
        for (int e = 0; e < 2; ++e) {
            const int s = kq * 2 + e;
            const float v = P2[0 * (SPB * H) + s * H + g] + P2[1 * (SPB * H) + s * H + g]
                          + P2[2 * (SPB * H) + s * H + g] + P2[3 * (SPB * H) + s * H + g];
            buf1[s * ZD + g] = buf0[s * ZD + g] + elu1(v);
        }
        // z = [h2, emb[sid]]: wave wid fills sample wid's 64 emb slots
        {
            const int st = sid[sbase + wid];
            buf1[wid * ZD + H + lane] = emb[st * HH + lane];
        }
        __syncthreads();
    }

    // ---- W1 GEMM (D=192, quarter=48) + LN1 + relu  (buf1 -> buf0) ----
    {
        float t[SPB] = {0,0,0,0,0,0,0,0};
        gemm_part<48, H, SPB>(W1 + (kq * 48) * H + g, buf1 + kq * 48, t);
#pragma unroll
        for (int s = 0; s < SPB; ++s) P2[kq * (SPB * H) + s * H + g] = t[s];
        __syncthreads();
        const float b1v = b1[g];
        float u[2];
#pragma unroll
        for (int e = 0; e < 2; ++e) {
            const int s = kq * 2 + e;
            u[e] = P2[0 * (SPB * H) + s * H + g] + P2[1 * (SPB * H) + s * H + g]
                 + P2[2 * (SPB * H) + s * H + g] + P2[3 * (SPB * H) + s * H + g] + b1v;
        }
        float su[2], sq[2];
#pragma unroll
        for (int e = 0; e < 2; ++e) { su[e] = u[e]; sq[e] = u[e] * u[e]; }
#pragma unroll
        for (int off = 32; off >= 1; off >>= 1) {
#pragma unroll
            for (int e = 0; e < 2; ++e) {
                su[e] += __shfl_xor(su[e], off, 64);
                sq[e] += __shfl_xor(sq[e], off, 64);
            }
        }
        if (lane == 0) {
            const int h = g >> 6;
#pragma unroll
            for (int e = 0; e < 2; ++e) {
                Rbuf[kq][h][e][0] = su[e];
                Rbuf[kq][h][e][1] = sq[e];
            }
        }
        __syncthreads();
        const float g1v = g1[g], be1v = be1[g];
#pragma unroll
        for (int e = 0; e < 2; ++e) {
            const int s = kq * 2 + e;
            const float tot = Rbuf[kq][0][e][0] + Rbuf[kq][1][e][0];
            const float tq  = Rbuf[kq][0][e][1] + Rbuf[kq][1][e][1];
            const float m   = tot * (1.f / H);
            const float var = tq * (1.f / H) - m * m;
            const float rs  = rsqrtf(var + LNEPS);
            buf0[s * ZD + g] = fmaxf((u[e] - m) * rs * g1v + be1v, 0.f);
        }
        __syncthreads();
    }

    // ---- W2 GEMM (D=128, 8-way K-split, out 64) + LN2 + out ----
    {
        const int c = lane;        // channel 0..63
        float t[SPB] = {0,0,0,0,0,0,0,0};
        gemm_part<16, HH, SPB>(W2 + (wid * 16) * HH + c, buf0 + wid * 16, t);
#pragma unroll
        for (int s = 0; s < SPB; ++s) P2[wid * (SPB * HH) + s * HH + c] = t[s];
        __syncthreads();
        // wave wid owns sample wid
        float v = b2[c];
#pragma unroll
        for (int k = 0; k < 8; ++k) v += P2[k * (SPB * HH) + wid * HH + c];
        float su = v, sq = v * v;
#pragma unroll
        for (int off = 32; off >= 1; off >>= 1) {
            su += __shfl_xor(su, off, 64);
            sq += __shfl_xor(sq, off, 64);
        }
        const float m   = su * (1.f / HH);
        const float var = sq * (1.f / HH) - m * m;
        const float rs  = rsqrtf(var + LNEPS);
        const float z2  = fmaxf((v - m) * rs * g2[c] + be2[c], 0.f);
        float po = z2 * Wo[c];
#pragma unroll
        for (int off = 32; off >= 1; off >>= 1) po += __shfl_xor(po, off, 64);
        if (lane == 0) out[sbase + wid] = po + bo[0];
    }
}

}  // namespace

extern "C" void kernel_launch(void* const* d_in, const int* in_sizes, int n_in,
                              void* d_out, int out_size, void* d_ws, size_t ws_size,
                              hipStream_t stream)
{
    const float* x    = (const float*)d_in[0];
    const int*   sid  = (const int*)d_in[1];
    // d_in[2] edge_index, d_in[3] edge_weight, d_in[8] gat_a: unused —
    // node-uniform broadcast + row-softmax makes the GAT aggregation collapse
    // to elu(h @ W) independent of the graph.
    const float* Wp   = (const float*)d_in[4];
    const float* bp   = (const float*)d_in[5];
    const float* emb  = (const float*)d_in[6];
    const float* gatW = (const float*)d_in[7];
    const float* W1   = (const float*)d_in[9];
    const float* b1   = (const float*)d_in[10];
    const float* g1   = (const float*)d_in[11];
    const float* be1  = (const float*)d_in[12];
    const float* W2   = (const float*)d_in[13];
    const float* b2   = (const float*)d_in[14];
    const float* g2   = (const float*)d_in[15];
    const float* be2  = (const float*)d_in[16];
    const float* Wo   = (const float*)d_in[17];
    const float* bo   = (const float*)d_in[18];
    float* out = (float*)d_out;

    dim3 grid(4096 / SPB);   // 512 blocks x 8 waves = 4096 waves = 4 waves/SIMD
    dim3 block(512);
    hipLaunchKernelGGL(fused_sthgat, grid, block, 0, stream,
                       x, sid, Wp, bp, emb, gatW, W1, b1, g1, be1,
                       W2, b2, g2, be2, Wo, bo, out);
}